// Round 12
// baseline (35.236 us; speedup 1.0000x reference)
//
#include <hip/hip_runtime.h>

#define IMG_H 720
#define IMG_W 1280
#define NPIX (IMG_H * IMG_W)
#define FX_C 800.0f
#define FY_C 800.0f
#define CX_C 640.0f
#define CY_C 360.0f

// Hot window around the projection center (640, 360).
// sigma_u = sigma_v ~= 11.4 px; +/-48 px ~= +/-4.2 sigma. Out-of-window points
// (~200 expected) take a test-and-skip global-atomic path, so correctness does
// NOT depend on the distribution.
#define WIN_W 96
#define WIN_H 96
#define WIN_X0 (640 - WIN_W / 2)  // 592
#define WIN_Y0 (360 - WIN_H / 2)  // 312
#define WIN_PIX (WIN_W * WIN_H)   // 9216
#define LDS_STRIDE 97             // pad: bank index must not be f(wx) only

#define SCAT_BLOCKS 256           // 1 block/CU (r10 proven best)
#define SCAT_THREADS 512
#define NGROUPS 32                // reduce1 groups; depth = 256/32 = 8
#define GDEPTH (SCAT_BLOCKS / NGROUPS)
#define EMPTY16 0xFFFFu
// Lessons: grid.sync() ~30us each on MI355X (r7). Narrow/serial window
// reductions cost more than the launch they save (r8, r9) — keep it WIDE.
// r11: more waves/SIMD didn't help (not latency-bound). r12: load pattern —
// 1 pt/thread => wave reads a CONTIGUOUS 768B span (12 lines/instr) vs the
// 8-pt float4 form whose 96B lane stride touched ~96 lines per instruction.

// K0: winner = -1 via int4 stores (rocclr fillBuffer kernel is ~40us-slow)
__global__ __launch_bounds__(256) void init_winner_kernel(int4* __restrict__ winner4,
                                                          int nquads) {
    int i = blockIdx.x * blockDim.x + threadIdx.x;
    if (i < nquads) winner4[i] = make_int4(-1, -1, -1, -1);
}

__device__ __forceinline__ void project_point(float x, float y, float zraw,
                                              float& u, float& v) {
    float z = __fadd_rn(zraw, 3.0f);
    // IEEE-exact, no FMA contraction: must bit-match numpy so floor() agrees
    u = __fadd_rn(__fmul_rn(FX_C, __fdiv_rn(x, z)), CX_C);
    v = __fadd_rn(__fmul_rn(FY_C, __fdiv_rn(y, z)), CY_C);
}

__device__ __forceinline__ void splat_one(int i, int base, float x, float y,
                                          float zraw, int* lwin,
                                          int* __restrict__ winner) {
    float u, v;
    project_point(x, y, zraw, u, v);
    if (u >= 0.0f && u < (float)IMG_W && v >= 0.0f && v < (float)IMG_H) {
        int xi = (int)floorf(u);
        int yi = (int)floorf(v);
        int wx = xi - WIN_X0;
        int wy = yi - WIN_Y0;
        if ((unsigned)wx < WIN_W && (unsigned)wy < WIN_H) {
            atomicMax(&lwin[wy * LDS_STRIDE + wx], i - base);  // local offset
        } else {
            int pix = yi * IMG_W + xi;                         // rare fallback
            if (winner[pix] < i) atomicMax(&winner[pix], i);
        }
    }
}

// K1: LDS-privatized window scatter; flush local offsets as a ushort slice.
// 1 point/thread/iter: wave64 reads contiguous 768B per load instruction.
__global__ __launch_bounds__(SCAT_THREADS) void scatter_win_kernel(
        const float* __restrict__ pos, int* __restrict__ winner,
        unsigned short* __restrict__ blockwin, int n, int per_block) {
    __shared__ int lwin[WIN_H * LDS_STRIDE];
    for (int j = threadIdx.x; j < WIN_H * LDS_STRIDE; j += SCAT_THREADS) lwin[j] = -1;
    __syncthreads();

    int base = blockIdx.x * per_block;
    int end  = base + per_block;
    if (end > n) end = n;

    #pragma unroll 4
    for (int i = base + (int)threadIdx.x; i < end; i += SCAT_THREADS) {
        float x = pos[3 * i + 0];
        float y = pos[3 * i + 1];
        float z = pos[3 * i + 2];
        splat_one(i, base, x, y, z, lwin, winner);
    }
    __syncthreads();

    unsigned short* dst = blockwin + (size_t)blockIdx.x * WIN_PIX;
    for (int j = threadIdx.x; j < WIN_PIX; j += SCAT_THREADS) {
        int wy = j / WIN_W;
        int wx = j - wy * WIN_W;
        int v = lwin[wy * LDS_STRIDE + wx];
        dst[j] = (v < 0) ? (unsigned short)EMPTY16 : (unsigned short)v;
    }
}

// K2 (wide): reduce GDEPTH slices -> one int partial per (group, pixel).
// Highest non-empty slice in the group holds the group max (indices ascend
// with block id). Thread serves a PIXEL PAIR via one uint load per slice.
// grid = (NGROUPS, WIN_PIX/2/256 = 18)
__global__ __launch_bounds__(256) void reduce1_kernel(
        const unsigned short* __restrict__ blockwin, int* __restrict__ part2,
        int per_block) {
    int g  = blockIdx.x;
    int t  = blockIdx.y * 256 + threadIdx.x;      // pixel-pair index
    int p0 = t * 2;
    const unsigned short* src = blockwin + (size_t)(g * GDEPTH) * WIN_PIX + p0;
    int m0 = -1, m1 = -1;
    #pragma unroll
    for (int b = GDEPTH - 1; b >= 0; --b) {       // highest block first
        unsigned int w = *(const unsigned int*)(src + (size_t)b * WIN_PIX);
        unsigned int lo = w & 0xFFFFu, hi = w >> 16;
        int gb = (g * GDEPTH + b) * per_block;
        if (m0 < 0 && lo != EMPTY16) m0 = gb + (int)lo;
        if (m1 < 0 && hi != EMPTY16) m1 = gb + (int)hi;
    }
    *(int2*)(part2 + (size_t)g * WIN_PIX + p0) = make_int2(m0, m1);
}

__device__ __forceinline__ void shade_and_store(
        const float* __restrict__ pos, const float* __restrict__ scales,
        const float* __restrict__ colors, float* __restrict__ out, int p, int w) {
    float cr = 0.0f, cgr = 0.0f, cb = 0.0f;
    if (w >= 0) {
        float u, v;
        project_point(pos[3 * w], pos[3 * w + 1], pos[3 * w + 2], u, v);
        float dx = __fsub_rn(u, floorf(u));
        float dy = __fsub_rn(v, floorf(v));
        float rad = __fmul_rn(scales[3 * w], 100.0f);
        float num = __fadd_rn(__fmul_rn(dx, dx), __fmul_rn(dy, dy));
        float den = __fmul_rn(2.0f, __fmul_rn(rad, rad));
        float wgt = expf(-__fdiv_rn(num, den));
        cr  = __fmul_rn(colors[3 * w + 0], wgt);
        cgr = __fmul_rn(colors[3 * w + 1], wgt);
        cb  = __fmul_rn(colors[3 * w + 2], wgt);
    }
    out[3 * p + 0] = cr;
    out[3 * p + 1] = cgr;
    out[3 * p + 2] = cb;
}

// K3: resolve. Window pixels reduce the NGROUPS partials inline (coalesced
// across the wave); others read winner[].
__global__ __launch_bounds__(256) void resolve_kernel(
        const float* __restrict__ pos, const float* __restrict__ scales,
        const float* __restrict__ colors, const int* __restrict__ part2,
        const int* __restrict__ winner, float* __restrict__ out,
        int npix, int use_part2) {
    int p = blockIdx.x * blockDim.x + threadIdx.x;
    if (p >= npix) return;
    int py = p / IMG_W;
    int px = p - py * IMG_W;
    int wx = px - WIN_X0;
    int wy = py - WIN_Y0;
    int w;
    if (use_part2 && (unsigned)wx < WIN_W && (unsigned)wy < WIN_H) {
        int wp = wy * WIN_W + wx;
        int m = -1;
        #pragma unroll
        for (int g = 0; g < NGROUPS; ++g) {
            int v = part2[g * WIN_PIX + wp];
            m = v > m ? v : m;
        }
        w = m;
    } else {
        w = winner[p];
    }
    shade_and_store(pos, scales, colors, out, p, w);
}

// Fallback scatter (round-2 style) if workspace is too small.
__global__ void scatter_simple_kernel(const float* __restrict__ pos,
                                      int* __restrict__ winner, int n) {
    int gid = blockIdx.x * blockDim.x + threadIdx.x;
    if (gid >= n) return;
    int i = n - 1 - gid;
    float u, v;
    project_point(pos[3 * i], pos[3 * i + 1], pos[3 * i + 2], u, v);
    if (u >= 0.0f && u < (float)IMG_W && v >= 0.0f && v < (float)IMG_H) {
        int pix = (int)floorf(v) * IMG_W + (int)floorf(u);
        if (winner[pix] < i) atomicMax(&winner[pix], i);
    }
}

extern "C" void kernel_launch(void* const* d_in, const int* in_sizes, int n_in,
                              void* d_out, int out_size, void* d_ws, size_t ws_size,
                              hipStream_t stream) {
    // inputs: [0] camera_poses (unused), [1] positions, [2] scales, [3] colors
    const float* positions = (const float*)d_in[1];
    const float* scales    = (const float*)d_in[2];
    const float* colors    = (const float*)d_in[3];
    float* out = (float*)d_out;
    int n = in_sizes[1] / 3;

    const size_t winner_bytes   = (size_t)NPIX * sizeof(int);
    const size_t part2_bytes    = (size_t)NGROUPS * WIN_PIX * sizeof(int);
    const size_t blockwin_bytes = (size_t)SCAT_BLOCKS * WIN_PIX * sizeof(unsigned short);

    int* winner = (int*)d_ws;
    int per_block = ((n + SCAT_BLOCKS - 1) / SCAT_BLOCKS + 3) & ~3;

    // K0: init winner (921600 ints = 230400 int4; 900 blocks x 256 = exact)
    init_winner_kernel<<<NPIX / 4 / 256, 256, 0, stream>>>((int4*)winner, NPIX / 4);

    if (ws_size >= winner_bytes + part2_bytes + blockwin_bytes && per_block <= 0xFFFE) {
        int* part2 = (int*)((char*)d_ws + winner_bytes);
        unsigned short* blockwin =
            (unsigned short*)((char*)d_ws + winner_bytes + part2_bytes);

        scatter_win_kernel<<<SCAT_BLOCKS, SCAT_THREADS, 0, stream>>>(
            positions, winner, blockwin, n, per_block);
        dim3 g1(NGROUPS, WIN_PIX / 2 / 256);  // 32 x 18
        reduce1_kernel<<<g1, 256, 0, stream>>>(blockwin, part2, per_block);
        resolve_kernel<<<(NPIX + 255) / 256, 256, 0, stream>>>(
            positions, scales, colors, part2, winner, out, NPIX, 1);
    } else {
        scatter_simple_kernel<<<(n + 255) / 256, 256, 0, stream>>>(positions, winner, n);
        resolve_kernel<<<(NPIX + 255) / 256, 256, 0, stream>>>(
            positions, scales, colors, (const int*)winner /*unused*/, winner, out,
            NPIX, 0);
    }
}

// Round 13
// 31.531 us; speedup vs baseline: 1.1175x; 1.1175x over previous
//
#include <hip/hip_runtime.h>

#define IMG_H 720
#define IMG_W 1280
#define NPIX (IMG_H * IMG_W)
#define FX_C 800.0f
#define FY_C 800.0f
#define CX_C 640.0f
#define CY_C 360.0f

// Hot window around the projection center (640, 360).
// sigma_u = sigma_v ~= 11.4 px; +/-48 px ~= +/-4.2 sigma. Out-of-window points
// (~200 expected) take a test-and-skip global-atomic path, so correctness does
// NOT depend on the distribution.
#define WIN_W 96
#define WIN_H 96
#define WIN_X0 (640 - WIN_W / 2)  // 592
#define WIN_Y0 (360 - WIN_H / 2)  // 312
#define WIN_PIX (WIN_W * WIN_H)   // 9216
#define LDS_STRIDE 97             // pad: bank index must not be f(wx) only

#define SCAT_BLOCKS 256           // 1 block/CU (r10 proven best)
#define SCAT_THREADS 512          // 8 waves
#define NGROUPS 32                // reduce1 groups; depth = 256/32 = 8
#define GDEPTH (SCAT_BLOCKS / NGROUPS)
#define EMPTY16 0xFFFFu
// Lessons: grid.sync() ~30us each (r7). Keep reductions WIDE (r8,r9).
// r11: occupancy didn't help. r12: scalar loads worse (3x instrs).
// r13: scatter is TA-request-bound -> LDS-staged AoS-vec3 transpose:
// 6 contiguous 1KB wave loads (16 lines/instr) + wave-private LDS redistribute.

// K0: winner = -1 via int4 stores (rocclr fillBuffer kernel is ~40us-slow)
__global__ __launch_bounds__(256) void init_winner_kernel(int4* __restrict__ winner4,
                                                          int nquads) {
    int i = blockIdx.x * blockDim.x + threadIdx.x;
    if (i < nquads) winner4[i] = make_int4(-1, -1, -1, -1);
}

__device__ __forceinline__ void project_point(float x, float y, float zraw,
                                              float& u, float& v) {
    float z = __fadd_rn(zraw, 3.0f);
    // IEEE-exact, no FMA contraction: must bit-match numpy so floor() agrees
    u = __fadd_rn(__fmul_rn(FX_C, __fdiv_rn(x, z)), CX_C);
    v = __fadd_rn(__fmul_rn(FY_C, __fdiv_rn(y, z)), CY_C);
}

__device__ __forceinline__ void splat_one(int i, int base, float x, float y,
                                          float zraw, int* lwin,
                                          int* __restrict__ winner) {
    float u, v;
    project_point(x, y, zraw, u, v);
    if (u >= 0.0f && u < (float)IMG_W && v >= 0.0f && v < (float)IMG_H) {
        int xi = (int)floorf(u);
        int yi = (int)floorf(v);
        int wx = xi - WIN_X0;
        int wy = yi - WIN_Y0;
        if ((unsigned)wx < WIN_W && (unsigned)wy < WIN_H) {
            atomicMax(&lwin[wy * LDS_STRIDE + wx], i - base);  // local offset
        } else {
            int pix = yi * IMG_W + xi;                         // rare fallback
            if (winner[pix] < i) atomicMax(&winner[pix], i);
        }
    }
}

// K1: LDS-privatized window scatter; flush local offsets as a ushort slice.
// Main loop: per wave-iteration, 512 points (6KB) are loaded as 6 CONTIGUOUS
// 1KB float4 wave-loads, parked in a wave-private LDS slab, and re-read
// per-lane (96B each, 4-way bank conflict — cheap). Tail uses strided float4s.
__global__ __launch_bounds__(SCAT_THREADS) void scatter_win_kernel(
        const float* __restrict__ pos, int* __restrict__ winner,
        unsigned short* __restrict__ blockwin, int n, int per_block) {
    __shared__ int lwin[WIN_H * LDS_STRIDE];            // 37.25 KB
    __shared__ float stage[8][1536];                    // 48 KB (6KB per wave)
    for (int j = threadIdx.x; j < WIN_H * LDS_STRIDE; j += SCAT_THREADS) lwin[j] = -1;
    __syncthreads();

    int base = blockIdx.x * per_block;
    int end  = base + per_block;
    if (end > n) end = n;
    int count = end - base;
    if (count < 0) count = 0;
    int nmacro = count / 4096;                          // full 4096-pt block chunks

    const int wave = threadIdx.x >> 6;
    const int lane = threadIdx.x & 63;
    float* st = stage[wave];

    for (int it = 0; it < nmacro; ++it) {
        int chunk = base + it * 4096 + wave * 512;      // this wave's 512 points
        const float4* src = (const float4*)(pos + (size_t)chunk * 3);
        // 6 contiguous 1KB wave-loads (lane stride 16B)
        float4 v0 = src[0 * 64 + lane];
        float4 v1 = src[1 * 64 + lane];
        float4 v2 = src[2 * 64 + lane];
        float4 v3 = src[3 * 64 + lane];
        float4 v4 = src[4 * 64 + lane];
        float4 v5 = src[5 * 64 + lane];
        *(float4*)&st[0 * 256 + lane * 4] = v0;
        *(float4*)&st[1 * 256 + lane * 4] = v1;
        *(float4*)&st[2 * 256 + lane * 4] = v2;
        *(float4*)&st[3 * 256 + lane * 4] = v3;
        *(float4*)&st[4 * 256 + lane * 4] = v4;
        *(float4*)&st[5 * 256 + lane * 4] = v5;
        // lane's 8 points = floats [lane*24, lane*24+24)
        float4 r0 = *(const float4*)&st[lane * 24 + 0];
        float4 r1 = *(const float4*)&st[lane * 24 + 4];
        float4 r2 = *(const float4*)&st[lane * 24 + 8];
        float4 r3 = *(const float4*)&st[lane * 24 + 12];
        float4 r4 = *(const float4*)&st[lane * 24 + 16];
        float4 r5 = *(const float4*)&st[lane * 24 + 20];
        int i0 = chunk + lane * 8;
        splat_one(i0 + 0, base, r0.x, r0.y, r0.z, lwin, winner);
        splat_one(i0 + 1, base, r0.w, r1.x, r1.y, lwin, winner);
        splat_one(i0 + 2, base, r1.z, r1.w, r2.x, lwin, winner);
        splat_one(i0 + 3, base, r2.y, r2.z, r2.w, lwin, winner);
        splat_one(i0 + 4, base, r3.x, r3.y, r3.z, lwin, winner);
        splat_one(i0 + 5, base, r3.w, r4.x, r4.y, lwin, winner);
        splat_one(i0 + 6, base, r4.z, r4.w, r5.x, lwin, winner);
        splat_one(i0 + 7, base, r5.y, r5.z, r5.w, lwin, winner);
    }

    // tail: remaining points, r10-style 8-pt strided float4 path
    int tbase = base + nmacro * 4096;
    for (int i0 = tbase + (int)threadIdx.x * 8; i0 < end; i0 += SCAT_THREADS * 8) {
        if (i0 + 8 <= end) {
            const float4* p4 = (const float4*)(pos + 3 * (size_t)i0);
            float4 a = p4[0], b = p4[1], c = p4[2], d = p4[3], e = p4[4], f = p4[5];
            splat_one(i0 + 0, base, a.x, a.y, a.z, lwin, winner);
            splat_one(i0 + 1, base, a.w, b.x, b.y, lwin, winner);
            splat_one(i0 + 2, base, b.z, b.w, c.x, lwin, winner);
            splat_one(i0 + 3, base, c.y, c.z, c.w, lwin, winner);
            splat_one(i0 + 4, base, d.x, d.y, d.z, lwin, winner);
            splat_one(i0 + 5, base, d.w, e.x, e.y, lwin, winner);
            splat_one(i0 + 6, base, e.z, e.w, f.x, lwin, winner);
            splat_one(i0 + 7, base, f.y, f.z, f.w, lwin, winner);
        } else {
            for (int i = i0; i < end; ++i)
                splat_one(i, base, pos[3 * i], pos[3 * i + 1], pos[3 * i + 2],
                          lwin, winner);
        }
    }
    __syncthreads();

    unsigned short* dst = blockwin + (size_t)blockIdx.x * WIN_PIX;
    for (int j = threadIdx.x; j < WIN_PIX; j += SCAT_THREADS) {
        int wy = j / WIN_W;
        int wx = j - wy * WIN_W;
        int v = lwin[wy * LDS_STRIDE + wx];
        dst[j] = (v < 0) ? (unsigned short)EMPTY16 : (unsigned short)v;
    }
}

// K2 (wide): reduce GDEPTH slices -> one int partial per (group, pixel).
// Highest non-empty slice in the group holds the group max (indices ascend
// with block id). Thread serves a PIXEL PAIR via one uint load per slice.
// grid = (NGROUPS, WIN_PIX/2/256 = 18)
__global__ __launch_bounds__(256) void reduce1_kernel(
        const unsigned short* __restrict__ blockwin, int* __restrict__ part2,
        int per_block) {
    int g  = blockIdx.x;
    int t  = blockIdx.y * 256 + threadIdx.x;      // pixel-pair index
    int p0 = t * 2;
    const unsigned short* src = blockwin + (size_t)(g * GDEPTH) * WIN_PIX + p0;
    int m0 = -1, m1 = -1;
    #pragma unroll
    for (int b = GDEPTH - 1; b >= 0; --b) {       // highest block first
        unsigned int w = *(const unsigned int*)(src + (size_t)b * WIN_PIX);
        unsigned int lo = w & 0xFFFFu, hi = w >> 16;
        int gb = (g * GDEPTH + b) * per_block;
        if (m0 < 0 && lo != EMPTY16) m0 = gb + (int)lo;
        if (m1 < 0 && hi != EMPTY16) m1 = gb + (int)hi;
    }
    *(int2*)(part2 + (size_t)g * WIN_PIX + p0) = make_int2(m0, m1);
}

__device__ __forceinline__ void shade_and_store(
        const float* __restrict__ pos, const float* __restrict__ scales,
        const float* __restrict__ colors, float* __restrict__ out, int p, int w) {
    float cr = 0.0f, cgr = 0.0f, cb = 0.0f;
    if (w >= 0) {
        float u, v;
        project_point(pos[3 * w], pos[3 * w + 1], pos[3 * w + 2], u, v);
        float dx = __fsub_rn(u, floorf(u));
        float dy = __fsub_rn(v, floorf(v));
        float rad = __fmul_rn(scales[3 * w], 100.0f);
        float num = __fadd_rn(__fmul_rn(dx, dx), __fmul_rn(dy, dy));
        float den = __fmul_rn(2.0f, __fmul_rn(rad, rad));
        float wgt = expf(-__fdiv_rn(num, den));
        cr  = __fmul_rn(colors[3 * w + 0], wgt);
        cgr = __fmul_rn(colors[3 * w + 1], wgt);
        cb  = __fmul_rn(colors[3 * w + 2], wgt);
    }
    out[3 * p + 0] = cr;
    out[3 * p + 1] = cgr;
    out[3 * p + 2] = cb;
}

// K3: resolve. Window pixels reduce the NGROUPS partials inline (coalesced
// across the wave); others read winner[].
__global__ __launch_bounds__(256) void resolve_kernel(
        const float* __restrict__ pos, const float* __restrict__ scales,
        const float* __restrict__ colors, const int* __restrict__ part2,
        const int* __restrict__ winner, float* __restrict__ out,
        int npix, int use_part2) {
    int p = blockIdx.x * blockDim.x + threadIdx.x;
    if (p >= npix) return;
    int py = p / IMG_W;
    int px = p - py * IMG_W;
    int wx = px - WIN_X0;
    int wy = py - WIN_Y0;
    int w;
    if (use_part2 && (unsigned)wx < WIN_W && (unsigned)wy < WIN_H) {
        int wp = wy * WIN_W + wx;
        int m = -1;
        #pragma unroll
        for (int g = 0; g < NGROUPS; ++g) {
            int v = part2[g * WIN_PIX + wp];
            m = v > m ? v : m;
        }
        w = m;
    } else {
        w = winner[p];
    }
    shade_and_store(pos, scales, colors, out, p, w);
}

// Fallback scatter (round-2 style) if workspace is too small.
__global__ void scatter_simple_kernel(const float* __restrict__ pos,
                                      int* __restrict__ winner, int n) {
    int gid = blockIdx.x * blockDim.x + threadIdx.x;
    if (gid >= n) return;
    int i = n - 1 - gid;
    float u, v;
    project_point(pos[3 * i], pos[3 * i + 1], pos[3 * i + 2], u, v);
    if (u >= 0.0f && u < (float)IMG_W && v >= 0.0f && v < (float)IMG_H) {
        int pix = (int)floorf(v) * IMG_W + (int)floorf(u);
        if (winner[pix] < i) atomicMax(&winner[pix], i);
    }
}

extern "C" void kernel_launch(void* const* d_in, const int* in_sizes, int n_in,
                              void* d_out, int out_size, void* d_ws, size_t ws_size,
                              hipStream_t stream) {
    // inputs: [0] camera_poses (unused), [1] positions, [2] scales, [3] colors
    const float* positions = (const float*)d_in[1];
    const float* scales    = (const float*)d_in[2];
    const float* colors    = (const float*)d_in[3];
    float* out = (float*)d_out;
    int n = in_sizes[1] / 3;

    const size_t winner_bytes   = (size_t)NPIX * sizeof(int);
    const size_t part2_bytes    = (size_t)NGROUPS * WIN_PIX * sizeof(int);
    const size_t blockwin_bytes = (size_t)SCAT_BLOCKS * WIN_PIX * sizeof(unsigned short);

    int* winner = (int*)d_ws;
    int per_block = ((n + SCAT_BLOCKS - 1) / SCAT_BLOCKS + 3) & ~3;

    // K0: init winner (921600 ints = 230400 int4; 900 blocks x 256 = exact)
    init_winner_kernel<<<NPIX / 4 / 256, 256, 0, stream>>>((int4*)winner, NPIX / 4);

    if (ws_size >= winner_bytes + part2_bytes + blockwin_bytes && per_block <= 0xFFFE) {
        int* part2 = (int*)((char*)d_ws + winner_bytes);
        unsigned short* blockwin =
            (unsigned short*)((char*)d_ws + winner_bytes + part2_bytes);

        scatter_win_kernel<<<SCAT_BLOCKS, SCAT_THREADS, 0, stream>>>(
            positions, winner, blockwin, n, per_block);
        dim3 g1(NGROUPS, WIN_PIX / 2 / 256);  // 32 x 18
        reduce1_kernel<<<g1, 256, 0, stream>>>(blockwin, part2, per_block);
        resolve_kernel<<<(NPIX + 255) / 256, 256, 0, stream>>>(
            positions, scales, colors, part2, winner, out, NPIX, 1);
    } else {
        scatter_simple_kernel<<<(n + 255) / 256, 256, 0, stream>>>(positions, winner, n);
        resolve_kernel<<<(NPIX + 255) / 256, 256, 0, stream>>>(
            positions, scales, colors, (const int*)winner /*unused*/, winner, out,
            NPIX, 0);
    }
}

// Round 14
// 29.716 us; speedup vs baseline: 1.1858x; 1.0611x over previous
//
#include <hip/hip_runtime.h>

#define IMG_H 720
#define IMG_W 1280
#define NPIX (IMG_H * IMG_W)
#define FX_C 800.0f
#define FY_C 800.0f
#define CX_C 640.0f
#define CY_C 360.0f

// Hot window around the projection center (640, 360).
// sigma_u = sigma_v ~= 11.4 px; +/-48 px ~= +/-4.2 sigma. Out-of-window points
// (~200 expected) take a test-and-skip global-atomic path, so correctness does
// NOT depend on the distribution.
#define WIN_W 96
#define WIN_H 96
#define WIN_X0 (640 - WIN_W / 2)  // 592
#define WIN_Y0 (360 - WIN_H / 2)  // 312
#define WIN_PIX (WIN_W * WIN_H)   // 9216
#define LDS_STRIDE 97             // pad: bank index must not be f(wx) only

#define SCAT_BLOCKS 256           // one block per CU
#define SCAT_THREADS 512          // 8 waves/CU
#define NGROUPS 32                // reduce1 groups; depth = 256/32 = 8
#define GDEPTH (SCAT_BLOCKS / NGROUPS)
#define EMPTY16 0xFFFFu
// Lessons: grid.sync() ~30us each on MI355X (r7). Narrow/serial window
// reductions cost more than the launch they save (r8, r9) — keep it WIDE.
// r11 (more waves), r12 (scalar loads), r13 (LDS-staged transpose) all null
// or negative: scatter sits at a balanced issue/VALU/LDS/L3 floor. This is
// the r10 best configuration (29.8us), reverted byte-for-byte.

// K0: winner = -1 via int4 stores (rocclr fillBuffer kernel is ~40us-slow)
__global__ __launch_bounds__(256) void init_winner_kernel(int4* __restrict__ winner4,
                                                          int nquads) {
    int i = blockIdx.x * blockDim.x + threadIdx.x;
    if (i < nquads) winner4[i] = make_int4(-1, -1, -1, -1);
}

__device__ __forceinline__ void project_point(float x, float y, float zraw,
                                              float& u, float& v) {
    float z = __fadd_rn(zraw, 3.0f);
    // IEEE-exact, no FMA contraction: must bit-match numpy so floor() agrees
    u = __fadd_rn(__fmul_rn(FX_C, __fdiv_rn(x, z)), CX_C);
    v = __fadd_rn(__fmul_rn(FY_C, __fdiv_rn(y, z)), CY_C);
}

__device__ __forceinline__ void splat_one(int i, int base, float x, float y,
                                          float zraw, int* lwin,
                                          int* __restrict__ winner) {
    float u, v;
    project_point(x, y, zraw, u, v);
    if (u >= 0.0f && u < (float)IMG_W && v >= 0.0f && v < (float)IMG_H) {
        int xi = (int)floorf(u);
        int yi = (int)floorf(v);
        int wx = xi - WIN_X0;
        int wy = yi - WIN_Y0;
        if ((unsigned)wx < WIN_W && (unsigned)wy < WIN_H) {
            atomicMax(&lwin[wy * LDS_STRIDE + wx], i - base);  // local offset
        } else {
            int pix = yi * IMG_W + xi;                         // rare fallback
            if (winner[pix] < i) atomicMax(&winner[pix], i);
        }
    }
}

// K1: LDS-privatized window scatter; flush local offsets as a ushort slice.
__global__ __launch_bounds__(SCAT_THREADS) void scatter_win_kernel(
        const float* __restrict__ pos, int* __restrict__ winner,
        unsigned short* __restrict__ blockwin, int n, int per_block) {
    __shared__ int lwin[WIN_H * LDS_STRIDE];
    for (int j = threadIdx.x; j < WIN_H * LDS_STRIDE; j += SCAT_THREADS) lwin[j] = -1;
    __syncthreads();

    int base = blockIdx.x * per_block;
    int end  = base + per_block;
    if (end > n) end = n;

    for (int i0 = base + (int)threadIdx.x * 8; i0 < end; i0 += SCAT_THREADS * 8) {
        if (i0 + 8 <= end) {
            // 8 points = 96 contiguous bytes = 6 x float4 (16B-aligned: i0%8==0)
            const float4* p4 = (const float4*)(pos + 3 * i0);
            float4 a = p4[0], b = p4[1], c = p4[2], d = p4[3], e = p4[4], f = p4[5];
            splat_one(i0 + 0, base, a.x, a.y, a.z, lwin, winner);
            splat_one(i0 + 1, base, a.w, b.x, b.y, lwin, winner);
            splat_one(i0 + 2, base, b.z, b.w, c.x, lwin, winner);
            splat_one(i0 + 3, base, c.y, c.z, c.w, lwin, winner);
            splat_one(i0 + 4, base, d.x, d.y, d.z, lwin, winner);
            splat_one(i0 + 5, base, d.w, e.x, e.y, lwin, winner);
            splat_one(i0 + 6, base, e.z, e.w, f.x, lwin, winner);
            splat_one(i0 + 7, base, f.y, f.z, f.w, lwin, winner);
        } else {
            for (int i = i0; i < end; ++i)
                splat_one(i, base, pos[3 * i], pos[3 * i + 1], pos[3 * i + 2],
                          lwin, winner);
        }
    }
    __syncthreads();

    unsigned short* dst = blockwin + (size_t)blockIdx.x * WIN_PIX;
    for (int j = threadIdx.x; j < WIN_PIX; j += SCAT_THREADS) {
        int wy = j / WIN_W;
        int wx = j - wy * WIN_W;
        int v = lwin[wy * LDS_STRIDE + wx];
        dst[j] = (v < 0) ? (unsigned short)EMPTY16 : (unsigned short)v;
    }
}

// K2 (wide): reduce GDEPTH slices -> one int partial per (group, pixel).
// Highest non-empty slice in the group holds the group max (indices ascend
// with block id). Thread serves a PIXEL PAIR via one uint load per slice.
// grid = (NGROUPS, WIN_PIX/2/256 = 18)
__global__ __launch_bounds__(256) void reduce1_kernel(
        const unsigned short* __restrict__ blockwin, int* __restrict__ part2,
        int per_block) {
    int g  = blockIdx.x;
    int t  = blockIdx.y * 256 + threadIdx.x;      // pixel-pair index
    int p0 = t * 2;
    const unsigned short* src = blockwin + (size_t)(g * GDEPTH) * WIN_PIX + p0;
    int m0 = -1, m1 = -1;
    #pragma unroll
    for (int b = GDEPTH - 1; b >= 0; --b) {       // highest block first
        unsigned int w = *(const unsigned int*)(src + (size_t)b * WIN_PIX);
        unsigned int lo = w & 0xFFFFu, hi = w >> 16;
        int gb = (g * GDEPTH + b) * per_block;
        if (m0 < 0 && lo != EMPTY16) m0 = gb + (int)lo;
        if (m1 < 0 && hi != EMPTY16) m1 = gb + (int)hi;
    }
    *(int2*)(part2 + (size_t)g * WIN_PIX + p0) = make_int2(m0, m1);
}

__device__ __forceinline__ void shade_and_store(
        const float* __restrict__ pos, const float* __restrict__ scales,
        const float* __restrict__ colors, float* __restrict__ out, int p, int w) {
    float cr = 0.0f, cgr = 0.0f, cb = 0.0f;
    if (w >= 0) {
        float u, v;
        project_point(pos[3 * w], pos[3 * w + 1], pos[3 * w + 2], u, v);
        float dx = __fsub_rn(u, floorf(u));
        float dy = __fsub_rn(v, floorf(v));
        float rad = __fmul_rn(scales[3 * w], 100.0f);
        float num = __fadd_rn(__fmul_rn(dx, dx), __fmul_rn(dy, dy));
        float den = __fmul_rn(2.0f, __fmul_rn(rad, rad));
        float wgt = expf(-__fdiv_rn(num, den));
        cr  = __fmul_rn(colors[3 * w + 0], wgt);
        cgr = __fmul_rn(colors[3 * w + 1], wgt);
        cb  = __fmul_rn(colors[3 * w + 2], wgt);
    }
    out[3 * p + 0] = cr;
    out[3 * p + 1] = cgr;
    out[3 * p + 2] = cb;
}

// K3: resolve. Window pixels reduce the NGROUPS partials inline (coalesced
// across the wave); others read winner[].
__global__ __launch_bounds__(256) void resolve_kernel(
        const float* __restrict__ pos, const float* __restrict__ scales,
        const float* __restrict__ colors, const int* __restrict__ part2,
        const int* __restrict__ winner, float* __restrict__ out,
        int npix, int use_part2) {
    int p = blockIdx.x * blockDim.x + threadIdx.x;
    if (p >= npix) return;
    int py = p / IMG_W;
    int px = p - py * IMG_W;
    int wx = px - WIN_X0;
    int wy = py - WIN_Y0;
    int w;
    if (use_part2 && (unsigned)wx < WIN_W && (unsigned)wy < WIN_H) {
        int wp = wy * WIN_W + wx;
        int m = -1;
        #pragma unroll
        for (int g = 0; g < NGROUPS; ++g) {
            int v = part2[g * WIN_PIX + wp];
            m = v > m ? v : m;
        }
        w = m;
    } else {
        w = winner[p];
    }
    shade_and_store(pos, scales, colors, out, p, w);
}

// Fallback scatter (round-2 style) if workspace is too small.
__global__ void scatter_simple_kernel(const float* __restrict__ pos,
                                      int* __restrict__ winner, int n) {
    int gid = blockIdx.x * blockDim.x + threadIdx.x;
    if (gid >= n) return;
    int i = n - 1 - gid;
    float u, v;
    project_point(pos[3 * i], pos[3 * i + 1], pos[3 * i + 2], u, v);
    if (u >= 0.0f && u < (float)IMG_W && v >= 0.0f && v < (float)IMG_H) {
        int pix = (int)floorf(v) * IMG_W + (int)floorf(u);
        if (winner[pix] < i) atomicMax(&winner[pix], i);
    }
}

extern "C" void kernel_launch(void* const* d_in, const int* in_sizes, int n_in,
                              void* d_out, int out_size, void* d_ws, size_t ws_size,
                              hipStream_t stream) {
    // inputs: [0] camera_poses (unused), [1] positions, [2] scales, [3] colors
    const float* positions = (const float*)d_in[1];
    const float* scales    = (const float*)d_in[2];
    const float* colors    = (const float*)d_in[3];
    float* out = (float*)d_out;
    int n = in_sizes[1] / 3;

    const size_t winner_bytes   = (size_t)NPIX * sizeof(int);
    const size_t part2_bytes    = (size_t)NGROUPS * WIN_PIX * sizeof(int);
    const size_t blockwin_bytes = (size_t)SCAT_BLOCKS * WIN_PIX * sizeof(unsigned short);

    int* winner = (int*)d_ws;
    int per_block = ((n + SCAT_BLOCKS - 1) / SCAT_BLOCKS + 7) & ~7;  // mult of 8

    // K0: init winner (921600 ints = 230400 int4; 900 blocks x 256 = exact)
    init_winner_kernel<<<NPIX / 4 / 256, 256, 0, stream>>>((int4*)winner, NPIX / 4);

    if (ws_size >= winner_bytes + part2_bytes + blockwin_bytes && per_block <= 0xFFFE) {
        int* part2 = (int*)((char*)d_ws + winner_bytes);
        unsigned short* blockwin =
            (unsigned short*)((char*)d_ws + winner_bytes + part2_bytes);

        scatter_win_kernel<<<SCAT_BLOCKS, SCAT_THREADS, 0, stream>>>(
            positions, winner, blockwin, n, per_block);
        dim3 g1(NGROUPS, WIN_PIX / 2 / 256);  // 32 x 18
        reduce1_kernel<<<g1, 256, 0, stream>>>(blockwin, part2, per_block);
        resolve_kernel<<<(NPIX + 255) / 256, 256, 0, stream>>>(
            positions, scales, colors, part2, winner, out, NPIX, 1);
    } else {
        scatter_simple_kernel<<<(n + 255) / 256, 256, 0, stream>>>(positions, winner, n);
        resolve_kernel<<<(NPIX + 255) / 256, 256, 0, stream>>>(
            positions, scales, colors, (const int*)winner /*unused*/, winner, out,
            NPIX, 0);
    }
}